// Round 23
// baseline (137.592 us; speedup 1.0000x reference)
//
#include <hip/hip_runtime.h>
#include <stdint.h>

#define HEADS 12
#define DMODEL 768
#define BATCH 2
#define SEQ 2048
#define BS (BATCH * SEQ)
#define HD 64
#define NT (SEQ / 64)

typedef float f32x4 __attribute__((ext_vector_type(4)));
typedef __bf16 bf16x8 __attribute__((ext_vector_type(8)));
typedef short s16x4 __attribute__((ext_vector_type(4)));
typedef short s16x8 __attribute__((ext_vector_type(8)));
typedef unsigned short u16;
typedef u16 u16x8 __attribute__((ext_vector_type(8)));

__device__ __forceinline__ u16 f2b(float f) {
    return __builtin_bit_cast(u16, (__bf16)f);
}

__device__ __forceinline__ void gld_lds16(const void* g, void* l) {
    __builtin_amdgcn_global_load_lds(
        (__attribute__((address_space(1))) void*)(g),
        (__attribute__((address_space(3))) void*)(l), 16, 0, 0);
}
__device__ __forceinline__ void gld_lds4(const void* g, void* l) {
    __builtin_amdgcn_global_load_lds(
        (__attribute__((address_space(1))) void*)(g),
        (__attribute__((address_space(3))) void*)(l), 4, 0, 0);
}

// ---------------- prep: W -> W^T bf16 ----------------
__global__ void cvt_wt(const float* __restrict__ wq, const float* __restrict__ wk,
                       const float* __restrict__ wv,
                       u16* __restrict__ tq, u16* __restrict__ tk, u16* __restrict__ tv) {
    int z = blockIdx.z;
    const float* w = (z == 0) ? wq : (z == 1) ? wk : wv;
    u16* t = (z == 0) ? tq : (z == 1) ? tk : tv;
    __shared__ float tile[32][33];
    int tx = threadIdx.x, ty = threadIdx.y;
    int kb = blockIdx.y * 32, nb = blockIdx.x * 32;
    for (int r = 0; r < 32; r += 8)
        tile[ty + r][tx] = w[(size_t)(kb + ty + r) * DMODEL + nb + tx];
    __syncthreads();
    for (int r = 0; r < 32; r += 8)
        t[(size_t)(nb + ty + r) * DMODEL + kb + tx] = f2b(tile[tx][ty + r]);
}

// ---------------- projection GEMM: C[m][n] = X_fp32[m][k] * W[k][n] ------------
// cvt_x fused (A reg-staged fp32 -> bf16 -> swizzled ds_write). 128x96 tile ->
// grid 32x8x3 = 768 blocks = exactly 3/CU. z=0 -> qw pre-scaled by 0.125*log2e;
// z=1 -> kw; z=2 -> vt [B,H,64,S] via swapped-operand MFMA (C^T, coalesced).
__global__ __launch_bounds__(256, 3) void proj_gemm(
    const float* __restrict__ xq, const float* __restrict__ xk, const float* __restrict__ xv,
    const u16* __restrict__ tq, const u16* __restrict__ tk, const u16* __restrict__ tv,
    u16* __restrict__ oq, u16* __restrict__ ok, u16* __restrict__ ov) {
    const int z = blockIdx.z;
    const float* X = (z == 0) ? xq : (z == 1) ? xk : xv;
    const u16* WT = (z == 0) ? tq : (z == 1) ? tk : tv;
    u16* Out      = (z == 0) ? oq : (z == 1) ? ok : ov;

    __shared__ u16 As[128 * 64];   // 16 KB
    __shared__ u16 Bs[96 * 64];    // 12 KB

    const int tid = threadIdx.x;
    const int lane = tid & 63, w = tid >> 6;
    const int wm = w >> 1, wn = w & 1;          // wave tile: 64 m x 48 n
    const int m0 = blockIdx.x * 128, n0 = blockIdx.y * 96;

    f32x4 acc[4][3] = {};

    for (int kt = 0; kt < DMODEL / 64; ++kt) {
        float4 xa[4], xb[4];
#pragma unroll
        for (int p = 0; p < 4; ++p) {
            int o = (p * 4 + w) * 1024 + lane * 16;
            int row = o >> 7, colb = o & 127;
            const float* src = X + (size_t)(m0 + row) * DMODEL + kt * 64 + (colb >> 1);
            xa[p] = *(const float4*)(src);
            xb[p] = *(const float4*)(src + 4);
        }
#pragma unroll
        for (int p = 0; p < 3; ++p) {
            int o = (p * 4 + w) * 1024 + lane * 16;
            int row = o >> 7;
            int col = (o & 127) ^ ((row & 7) << 4);
            gld_lds16((const char*)WT + (size_t)(n0 + row) * (DMODEL * 2) + kt * 128 + col,
                      (char*)Bs + (p * 4 + w) * 1024);
        }
#pragma unroll
        for (int p = 0; p < 4; ++p) {
            int o = (p * 4 + w) * 1024 + lane * 16;
            int row = o >> 7, colb = o & 127;
            u16x8 v8;
            v8[0] = f2b(xa[p].x); v8[1] = f2b(xa[p].y);
            v8[2] = f2b(xa[p].z); v8[3] = f2b(xa[p].w);
            v8[4] = f2b(xb[p].x); v8[5] = f2b(xb[p].y);
            v8[6] = f2b(xb[p].z); v8[7] = f2b(xb[p].w);
            *(u16x8*)((char*)As + row * 128 + (colb ^ ((row & 7) << 4))) = v8;
        }
        __syncthreads();
#pragma unroll
        for (int kk = 0; kk < 2; ++kk) {
            bf16x8 af[4], bfr[3];
#pragma unroll
            for (int mi = 0; mi < 4; ++mi) {
                int row = wm * 64 + mi * 16 + (lane & 15);
                int col = (kk * 64 + ((lane >> 4) << 4)) ^ ((row & 7) << 4);
                af[mi] = *(const bf16x8*)((const char*)As + row * 128 + col);
            }
#pragma unroll
            for (int ni = 0; ni < 3; ++ni) {
                int row = wn * 48 + ni * 16 + (lane & 15);
                int col = (kk * 64 + ((lane >> 4) << 4)) ^ ((row & 7) << 4);
                bfr[ni] = *(const bf16x8*)((const char*)Bs + row * 128 + col);
            }
            if (z == 2) {
#pragma unroll
                for (int mi = 0; mi < 4; ++mi)
#pragma unroll
                    for (int ni = 0; ni < 3; ++ni)
                        acc[mi][ni] = __builtin_amdgcn_mfma_f32_16x16x32_bf16(
                            bfr[ni], af[mi], acc[mi][ni], 0, 0, 0);   // C^T fragments
            } else {
#pragma unroll
                for (int mi = 0; mi < 4; ++mi)
#pragma unroll
                    for (int ni = 0; ni < 3; ++ni)
                        acc[mi][ni] = __builtin_amdgcn_mfma_f32_16x16x32_bf16(
                            af[mi], bfr[ni], acc[mi][ni], 0, 0, 0);
            }
        }
        __syncthreads();
    }

    if (z == 2) {
        const int m = m0 + wm * 64 + (tid & 15);
        const int b = m >> 11;
#pragma unroll
        for (int mi = 0; mi < 4; ++mi) {
            int s = ((m + mi * 16) & 2047);
#pragma unroll
            for (int ni = 0; ni < 3; ++ni) {
                int nb2 = n0 + wn * 48 + ni * 16 + (((tid & 63) >> 4) << 2);
#pragma unroll
                for (int r = 0; r < 4; ++r) {
                    int n = nb2 + r;
                    int h = n >> 6, dd = n & 63;
                    Out[((size_t)(b * HEADS + h) * HD + dd) * SEQ + s] =
                        f2b(acc[mi][ni][r]);
                }
            }
        }
    } else {
        const float mul = (z == 0) ? 0.125f * 1.44269504f : 1.0f;
#pragma unroll
        for (int mi = 0; mi < 4; ++mi) {
            int mb = m0 + wm * 64 + mi * 16 + (((tid & 63) >> 4) << 2);
#pragma unroll
            for (int ni = 0; ni < 3; ++ni) {
                int n = n0 + wn * 48 + ni * 16 + (tid & 15);
                int h = n >> 6, dd = n & 63;
#pragma unroll
                for (int r = 0; r < 4; ++r) {
                    int m = mb + r;
                    int b = m >> 11, s = m & 2047;
                    Out[((size_t)(b * HEADS + h) * SEQ + s) * HD + dd] =
                        f2b(acc[mi][ni][r] * mul);
                }
            }
        }
    }
}

// per-tile compute, MACRO-inlined (direct array writes — no pointer params;
// lambda out-params put pbA/vvA in scratch in round 22, rule-#20 corollary)
#define TILE_QK(P, PB, VV)                                                      \
    {                                                                           \
        const char* KsC = smem + (P) * 8192;                                    \
        const char* VsC = smem + 16384 + (P) * 8192;                            \
        const float* biasC = (const float*)(smem + 32768 + (P) * 256);          \
        bf16x8 kf0, kf1;                                                        \
        {                                                                       \
            int row = w16 + l15;                                                \
            kf0 = *(const bf16x8*)(KsC + row * 128 +                            \
                                   (((g << 4)) ^ ((row & 7) << 4)));            \
            kf1 = *(const bf16x8*)(KsC + row * 128 +                            \
                                   ((64 + (g << 4)) ^ ((row & 7) << 4)));       \
        }                                                                       \
        _Pragma("unroll")                                                       \
        for (int dt = 0; dt < 4; ++dt) {                                        \
            int row = dt * 16 + l15;                                            \
            VV[dt] = *(const s16x4*)(VsC + row * 128 +                          \
                                     ((w16 * 2 + g * 8) ^ ((row & 7) << 4)));   \
        }                                                                       \
        f32x4 vm = *(const f32x4*)(biasC + w16 + 4 * g);                        \
        f32x4 sc[4] = {};                                                       \
        _Pragma("unroll")                                                       \
        for (int qs = 0; qs < 4; ++qs)                                          \
            sc[qs] = __builtin_amdgcn_mfma_f32_16x16x32_bf16(                   \
                kf0, qf[qs][0], sc[qs], 0, 0, 0);                               \
        _Pragma("unroll")                                                       \
        for (int qs = 0; qs < 4; ++qs)                                          \
            sc[qs] = __builtin_amdgcn_mfma_f32_16x16x32_bf16(                   \
                kf1, qf[qs][1], sc[qs], 0, 0, 0);                               \
        int mv_ok = (vm[0] == 1.f) & (vm[1] == 1.f) & (vm[2] == 1.f) & (vm[3] == 1.f); \
        if (!__all(mv_ok)) {                                                    \
            f32x4 bbv;                                                          \
            _Pragma("unroll")                                                   \
            for (int r = 0; r < 4; ++r)                                         \
                bbv[r] = fmaf(vm[r], 1.442695e10f, -1.442695e10f);              \
            _Pragma("unroll")                                                   \
            for (int qs = 0; qs < 4; ++qs)                                      \
                _Pragma("unroll")                                               \
                for (int r = 0; r < 4; ++r)                                     \
                    sc[qs][r] += bbv[r];                                        \
        }                                                                       \
        _Pragma("unroll")                                                       \
        for (int qs = 0; qs < 4; ++qs)                                          \
            _Pragma("unroll")                                                   \
            for (int r = 0; r < 4; ++r)                                         \
                PB[qs][r] = (short)f2b(__builtin_amdgcn_exp2f(sc[qs][r]));      \
    }

// ---------------- fused attention (key-split + pair-unrolled K=32 PV) ----------
// Round-20 proven structure; round-23: PV/lsum once per TILE PAIR at K=32
// (k-slot 8g+j: j=r -> tile A, j=4+r -> tile B; concat regs = valid fragments;
// math HW-verified in round 21). Tile bodies macro-inlined with direct array
// writes to avoid the round-21/22 scratch demotions.
// qw: [B,H,S,64] bf16 pre-scaled by 0.125*log2e; kw: [B,H,S,64]; vt: [B,H,64,S]
__global__ __launch_bounds__(256, 3) void attn(
    const u16* __restrict__ qw, const u16* __restrict__ kw, const u16* __restrict__ vt,
    const float* __restrict__ v_mask, const float* __restrict__ q_mask,
    float* __restrict__ out) {
    // loop phase:  Ks[2] 16KB | Vs[2] 16KB | bias[2] 512B   (33,280 B)
    // epilogue:    buf 48KB ([4 qs][3 j][16 q][64 d] f32) | lred 1KB
    __shared__ __align__(16) char smem[50176];

    const int tid = threadIdx.x;
    const int lane = tid & 63, w = tid >> 6;
    const int l15 = lane & 15, g = lane >> 4;
    const int w16 = w * 16;
    const int bh = blockIdx.y;
    const int b = bh / HEADS, h = bh % HEADS;
    const int q0 = blockIdx.x * 64;

    const u16* qb = qw + (size_t)bh * SEQ * HD;
    const u16* kb = kw + (size_t)bh * SEQ * HD;
    const u16* vb = vt + (size_t)bh * HD * SEQ;
    const float* vmaskb = v_mask + (size_t)b * SEQ;

    bf16x8 qf[4][2];
#pragma unroll
    for (int qs = 0; qs < 4; ++qs)
#pragma unroll
        for (int kk = 0; kk < 2; ++kk) {
            int row = q0 + qs * 16 + l15;
            qf[qs][kk] = *(const bf16x8*)((const char*)qb + (size_t)row * 128 + kk * 64 + (g << 4));
        }

    s16x8 ones8;
#pragma unroll
    for (int r = 0; r < 8; ++r) ones8[r] = (short)0x3F80;

    f32x4 accO[4][4] = {};
    f32x4 lacc[4] = {};            // l[q=l15] replicated across rows

    auto stage = [&](int t, int p) {
        const int kv0 = t * 64;
#pragma unroll
        for (int i = 0; i < 2; ++i) {
            int o = (i * 4 + w) * 1024 + lane * 16;
            int row = o >> 7;
            int col = (o & 127) ^ ((row & 7) << 4);
            gld_lds16((const char*)kb + (size_t)(kv0 + row) * 128 + col,
                      smem + p * 8192 + (i * 4 + w) * 1024);
            gld_lds16((const char*)vb + (size_t)row * (SEQ * 2) + (size_t)kv0 * 2 + col,
                      smem + 16384 + p * 8192 + (i * 4 + w) * 1024);
        }
        gld_lds4(vmaskb + kv0 + lane, smem + 32768 + p * 256);
    };

    stage(0, 0);
    __syncthreads();

    for (int u = 0; u < NT / 2; ++u) {
        // ---- tile A = 2u (buffer 0)
        stage(2 * u + 1, 1);
        s16x4 pbA[4], vvA[4];
        TILE_QK(0, pbA, vvA)
        __syncthreads();                      // buf1 staged; buf0 reads done

        // ---- tile B = 2u+1 (buffer 1)
        if (u + 1 < NT / 2) stage(2 * u + 2, 0);
        s16x4 pbB[4], vvB[4];
        TILE_QK(1, pbB, vvB)

        // ---- ONE K=32 PV + lsum over the pair (all operands in registers)
        bf16x8 va8[4], pb8[4];
#pragma unroll
        for (int dt = 0; dt < 4; ++dt) {
            s16x8 vcat;
#pragma unroll
            for (int r = 0; r < 4; ++r) { vcat[r] = vvA[dt][r]; vcat[r + 4] = vvB[dt][r]; }
            va8[dt] = __builtin_bit_cast(bf16x8, vcat);
        }
#pragma unroll
        for (int qs = 0; qs < 4; ++qs) {
            s16x8 pcat;
#pragma unroll
            for (int r = 0; r < 4; ++r) { pcat[r] = pbA[qs][r]; pcat[r + 4] = pbB[qs][r]; }
            pb8[qs] = __builtin_bit_cast(bf16x8, pcat);
        }
#pragma unroll
        for (int qs = 0; qs < 4; ++qs) {
#pragma unroll
            for (int dt = 0; dt < 4; ++dt)
                accO[qs][dt] = __builtin_amdgcn_mfma_f32_16x16x32_bf16(
                    va8[dt], pb8[qs], accO[qs][dt], 0, 0, 0);
            lacc[qs] = __builtin_amdgcn_mfma_f32_16x16x32_bf16(
                __builtin_bit_cast(bf16x8, ones8), pb8[qs], lacc[qs], 0, 0, 0);
        }
        __syncthreads();                      // buf0 staged; buf1 reads done
    }

    float lpart[4];
#pragma unroll
    for (int qs = 0; qs < 4; ++qs) lpart[qs] = lacc[qs][0];

    float* buf  = (float*)smem;                  // [qs][j][16 q][64 d]
    float* lred = (float*)(smem + 49152);        // [w][qs][16]

    if (g == 0)
#pragma unroll
        for (int qs = 0; qs < 4; ++qs)
            lred[(w * 4 + qs) * 16 + l15] = lpart[qs];

    f32x4 own[4] = {};
#pragma unroll
    for (int qs = 0; qs < 4; ++qs)
        if (qs == w) {
#pragma unroll
            for (int dt = 0; dt < 4; ++dt) own[dt] = accO[qs][dt];
        }

#pragma unroll
    for (int qs = 0; qs < 4; ++qs) {
        if (qs == w) continue;                   // runtime branch, static indices
        int j = (w < qs) ? w : w - 1;
        float* slot = buf + ((qs * 3 + j) * 16 + l15) * 64;
#pragma unroll
        for (int dt = 0; dt < 4; ++dt)
            *(f32x4*)(slot + dt * 16 + 4 * g) = accO[qs][dt];
    }
    __syncthreads();

    {
#pragma unroll
        for (int j = 0; j < 3; ++j) {
            const float* slot = buf + ((w * 3 + j) * 16 + l15) * 64;
#pragma unroll
            for (int dt = 0; dt < 4; ++dt)
                own[dt] += *(const f32x4*)(slot + dt * 16 + 4 * g);
        }
        float ltot = lred[(0 * 4 + w) * 16 + l15] + lred[(1 * 4 + w) * 16 + l15] +
                     lred[(2 * 4 + w) * 16 + l15] + lred[(3 * 4 + w) * 16 + l15];
        int qrow = q0 + w16 + l15;
        float qm = q_mask[(size_t)b * SEQ + qrow];
        float inv = (ltot > 0.f) ? qm / ltot : 0.f;
#pragma unroll
        for (int dt = 0; dt < 4; ++dt) {
            f32x4 o = own[dt] * inv;
            *(f32x4*)(&out[((size_t)b * SEQ + qrow) * 768 + h * HD + dt * 16 + 4 * g]) = o;
        }
    }
}

extern "C" void kernel_launch(void* const* d_in, const int* in_sizes, int n_in,
                              void* d_out, int out_size, void* d_ws, size_t ws_size,
                              hipStream_t stream) {
    const float* q      = (const float*)d_in[0];
    const float* k      = (const float*)d_in[1];
    const float* v      = (const float*)d_in[2];
    const float* vmask  = (const float*)d_in[3];
    const float* qmask  = (const float*)d_in[4];
    const float* Wq     = (const float*)d_in[5];
    const float* Wk     = (const float*)d_in[6];
    const float* Wv     = (const float*)d_in[7];
    float* out = (float*)d_out;

    u16* WTq = (u16*)d_ws;
    u16* WTk = WTq + (size_t)DMODEL * DMODEL;
    u16* WTv = WTk + (size_t)DMODEL * DMODEL;
    u16* qwp = WTv + (size_t)DMODEL * DMODEL;
    u16* kwp = qwp + (size_t)BATCH * HEADS * SEQ * HD;
    u16* vtp = kwp + (size_t)BATCH * HEADS * SEQ * HD;

    cvt_wt<<<dim3(DMODEL / 32, DMODEL / 32, 3), dim3(32, 8), 0, stream>>>(
        Wq, Wk, Wv, WTq, WTk, WTv);
    proj_gemm<<<dim3(BS / 128, DMODEL / 96, 3), 256, 0, stream>>>(
        q, k, v, WTq, WTk, WTv, qwp, kwp, vtp);
    attn<<<dim3(SEQ / 64, BATCH * HEADS), 256, 0, stream>>>(
        qwp, kwp, vtp, vmask, qmask, out);
}

// Round 24
// 82.709 us; speedup vs baseline: 1.6636x; 1.6636x over previous
//
#include <hip/hip_runtime.h>
#include <stdint.h>

#define HEADS 12
#define DMODEL 768
#define BATCH 2
#define SEQ 2048
#define BS (BATCH * SEQ)
#define HD 64

typedef float f32x4 __attribute__((ext_vector_type(4)));
typedef __bf16 bf16x8 __attribute__((ext_vector_type(8)));
typedef short s16x4 __attribute__((ext_vector_type(4)));
typedef unsigned short u16;
typedef u16 u16x8 __attribute__((ext_vector_type(8)));

__device__ __forceinline__ u16 f2b(float f) {
    return __builtin_bit_cast(u16, (__bf16)f);
}

__device__ __forceinline__ void gld_lds16(const void* g, void* l) {
    __builtin_amdgcn_global_load_lds(
        (__attribute__((address_space(1))) void*)(g),
        (__attribute__((address_space(3))) void*)(l), 16, 0, 0);
}
__device__ __forceinline__ void gld_lds4(const void* g, void* l) {
    __builtin_amdgcn_global_load_lds(
        (__attribute__((address_space(1))) void*)(g),
        (__attribute__((address_space(3))) void*)(l), 4, 0, 0);
}

// ---------------- prep: W -> W^T bf16 ----------------
__global__ void cvt_wt(const float* __restrict__ wq, const float* __restrict__ wk,
                       const float* __restrict__ wv,
                       u16* __restrict__ tq, u16* __restrict__ tk, u16* __restrict__ tv) {
    int z = blockIdx.z;
    const float* w = (z == 0) ? wq : (z == 1) ? wk : wv;
    u16* t = (z == 0) ? tq : (z == 1) ? tk : tv;
    __shared__ float tile[32][33];
    int tx = threadIdx.x, ty = threadIdx.y;
    int kb = blockIdx.y * 32, nb = blockIdx.x * 32;
    for (int r = 0; r < 32; r += 8)
        tile[ty + r][tx] = w[(size_t)(kb + ty + r) * DMODEL + nb + tx];
    __syncthreads();
    for (int r = 0; r < 32; r += 8)
        t[(size_t)(nb + ty + r) * DMODEL + kb + tx] = f2b(tile[tx][ty + r]);
}

// ---------------- projection GEMM: C[m][n] = X_fp32[m][k] * W[k][n] ------------
// cvt_x fused (A reg-staged fp32 -> bf16 -> swizzled ds_write). 128x96 tile ->
// grid 32x8x3 = 768 blocks = exactly 3/CU. z=0 -> qw pre-scaled by 0.125*log2e;
// z=1 -> kw; z=2 -> vt [B,H,64,S] via swapped-operand MFMA (C^T, coalesced).
__global__ __launch_bounds__(256, 3) void proj_gemm(
    const float* __restrict__ xq, const float* __restrict__ xk, const float* __restrict__ xv,
    const u16* __restrict__ tq, const u16* __restrict__ tk, const u16* __restrict__ tv,
    u16* __restrict__ oq, u16* __restrict__ ok, u16* __restrict__ ov) {
    const int z = blockIdx.z;
    const float* X = (z == 0) ? xq : (z == 1) ? xk : xv;
    const u16* WT = (z == 0) ? tq : (z == 1) ? tk : tv;
    u16* Out      = (z == 0) ? oq : (z == 1) ? ok : ov;

    __shared__ u16 As[128 * 64];   // 16 KB
    __shared__ u16 Bs[96 * 64];    // 12 KB

    const int tid = threadIdx.x;
    const int lane = tid & 63, w = tid >> 6;
    const int wm = w >> 1, wn = w & 1;          // wave tile: 64 m x 48 n
    const int m0 = blockIdx.x * 128, n0 = blockIdx.y * 96;

    f32x4 acc[4][3] = {};

    for (int kt = 0; kt < DMODEL / 64; ++kt) {
        float4 xa[4], xb[4];
#pragma unroll
        for (int p = 0; p < 4; ++p) {
            int o = (p * 4 + w) * 1024 + lane * 16;
            int row = o >> 7, colb = o & 127;
            const float* src = X + (size_t)(m0 + row) * DMODEL + kt * 64 + (colb >> 1);
            xa[p] = *(const float4*)(src);
            xb[p] = *(const float4*)(src + 4);
        }
#pragma unroll
        for (int p = 0; p < 3; ++p) {
            int o = (p * 4 + w) * 1024 + lane * 16;
            int row = o >> 7;
            int col = (o & 127) ^ ((row & 7) << 4);
            gld_lds16((const char*)WT + (size_t)(n0 + row) * (DMODEL * 2) + kt * 128 + col,
                      (char*)Bs + (p * 4 + w) * 1024);
        }
#pragma unroll
        for (int p = 0; p < 4; ++p) {
            int o = (p * 4 + w) * 1024 + lane * 16;
            int row = o >> 7, colb = o & 127;
            u16x8 v8;
            v8[0] = f2b(xa[p].x); v8[1] = f2b(xa[p].y);
            v8[2] = f2b(xa[p].z); v8[3] = f2b(xa[p].w);
            v8[4] = f2b(xb[p].x); v8[5] = f2b(xb[p].y);
            v8[6] = f2b(xb[p].z); v8[7] = f2b(xb[p].w);
            *(u16x8*)((char*)As + row * 128 + (colb ^ ((row & 7) << 4))) = v8;
        }
        __syncthreads();
#pragma unroll
        for (int kk = 0; kk < 2; ++kk) {
            bf16x8 af[4], bfr[3];
#pragma unroll
            for (int mi = 0; mi < 4; ++mi) {
                int row = wm * 64 + mi * 16 + (lane & 15);
                int col = (kk * 64 + ((lane >> 4) << 4)) ^ ((row & 7) << 4);
                af[mi] = *(const bf16x8*)((const char*)As + row * 128 + col);
            }
#pragma unroll
            for (int ni = 0; ni < 3; ++ni) {
                int row = wn * 48 + ni * 16 + (lane & 15);
                int col = (kk * 64 + ((lane >> 4) << 4)) ^ ((row & 7) << 4);
                bfr[ni] = *(const bf16x8*)((const char*)Bs + row * 128 + col);
            }
            if (z == 2) {
#pragma unroll
                for (int mi = 0; mi < 4; ++mi)
#pragma unroll
                    for (int ni = 0; ni < 3; ++ni)
                        acc[mi][ni] = __builtin_amdgcn_mfma_f32_16x16x32_bf16(
                            bfr[ni], af[mi], acc[mi][ni], 0, 0, 0);   // C^T fragments
            } else {
#pragma unroll
                for (int mi = 0; mi < 4; ++mi)
#pragma unroll
                    for (int ni = 0; ni < 3; ++ni)
                        acc[mi][ni] = __builtin_amdgcn_mfma_f32_16x16x32_bf16(
                            af[mi], bfr[ni], acc[mi][ni], 0, 0, 0);
            }
        }
        __syncthreads();
    }

    if (z == 2) {
        const int m = m0 + wm * 64 + (tid & 15);
        const int b = m >> 11;
#pragma unroll
        for (int mi = 0; mi < 4; ++mi) {
            int s = ((m + mi * 16) & 2047);
#pragma unroll
            for (int ni = 0; ni < 3; ++ni) {
                int nb2 = n0 + wn * 48 + ni * 16 + (((tid & 63) >> 4) << 2);
#pragma unroll
                for (int r = 0; r < 4; ++r) {
                    int n = nb2 + r;
                    int h = n >> 6, dd = n & 63;
                    Out[((size_t)(b * HEADS + h) * HD + dd) * SEQ + s] =
                        f2b(acc[mi][ni][r]);
                }
            }
        }
    } else {
        const float mul = (z == 0) ? 0.125f * 1.44269504f : 1.0f;
#pragma unroll
        for (int mi = 0; mi < 4; ++mi) {
            int mb = m0 + wm * 64 + mi * 16 + (((tid & 63) >> 4) << 2);
#pragma unroll
            for (int ni = 0; ni < 3; ++ni) {
                int n = n0 + wn * 48 + ni * 16 + (tid & 15);
                int h = n >> 6, dd = n & 63;
#pragma unroll
                for (int r = 0; r < 4; ++r) {
                    int m = mb + r;
                    int b = m >> 11, s = m & 2047;
                    Out[((size_t)(b * HEADS + h) * SEQ + s) * HD + dd] =
                        f2b(acc[mi][ni][r] * mul);
                }
            }
        }
    }
}

// ---------------- fused attention (round-20 proven: key-split + VALU diet) -----
// Block = 64 q rows, 4 waves; wave w owns keys 16w..16w+15 of every tile vs all
// 64 q. Fixed-max softmax -> additive partials -> single cross-wave combine.
// l computed via all-ones-A MFMA (lane-resident l[q=l15], no shuffle-reduce);
// wave-uniform all-ones v_mask fast path skips bias math (exact when v==1).
// qw: [B,H,S,64] bf16 pre-scaled by 0.125*log2e; kw: [B,H,S,64]; vt: [B,H,64,S]
__global__ __launch_bounds__(256, 3) void attn(
    const u16* __restrict__ qw, const u16* __restrict__ kw, const u16* __restrict__ vt,
    const float* __restrict__ v_mask, const float* __restrict__ q_mask,
    float* __restrict__ out) {
    // loop phase:  Ks[2] 16KB | Vs[2] 16KB | bias[2] 512B   (33,280 B)
    // epilogue:    buf 48KB ([4 qs][3 j][16 q][64 d] f32) | lred 1KB
    __shared__ __align__(16) char smem[50176];

    const int tid = threadIdx.x;
    const int lane = tid & 63, w = tid >> 6;
    const int l15 = lane & 15, g = lane >> 4;
    const int w16 = w * 16;
    const int bh = blockIdx.y;
    const int b = bh / HEADS, h = bh % HEADS;
    const int q0 = blockIdx.x * 64;

    const u16* qb = qw + (size_t)bh * SEQ * HD;
    const u16* kb = kw + (size_t)bh * SEQ * HD;
    const u16* vb = vt + (size_t)bh * HD * SEQ;
    const float* vmaskb = v_mask + (size_t)b * SEQ;

    bf16x8 qf[4][2];
#pragma unroll
    for (int qs = 0; qs < 4; ++qs)
#pragma unroll
        for (int kk = 0; kk < 2; ++kk) {
            int row = q0 + qs * 16 + l15;
            qf[qs][kk] = *(const bf16x8*)((const char*)qb + (size_t)row * 128 + kk * 64 + (g << 4));
        }

    // all-ones bf16 A-fragment for the l-sum MFMA
    s16x4 ones4;
#pragma unroll
    for (int r = 0; r < 4; ++r) ones4[r] = (short)0x3F80;

    f32x4 accO[4][4] = {};
    f32x4 lacc[4] = {};            // lacc[qs][r] -> l[q=l15] (all rows identical)
    float lpart[4];

    auto stage = [&](int t, int p) {
        const int kv0 = t * 64;
#pragma unroll
        for (int i = 0; i < 2; ++i) {
            int o = (i * 4 + w) * 1024 + lane * 16;
            int row = o >> 7;
            int col = (o & 127) ^ ((row & 7) << 4);
            gld_lds16((const char*)kb + (size_t)(kv0 + row) * 128 + col,
                      smem + p * 8192 + (i * 4 + w) * 1024);
            gld_lds16((const char*)vb + (size_t)row * (SEQ * 2) + (size_t)kv0 * 2 + col,
                      smem + 16384 + p * 8192 + (i * 4 + w) * 1024);
        }
        gld_lds4(vmaskb + kv0 + lane, smem + 32768 + p * 256);
    };

    stage(0, 0);
    __syncthreads();

    for (int t = 0; t < SEQ / 64; ++t) {
        const int cur = t & 1;
        if (t + 1 < SEQ / 64) stage(t + 1, cur ^ 1);
        const char* KsC = smem + cur * 8192;
        const char* VsC = smem + 16384 + cur * 8192;
        const float* biasC = (const float*)(smem + 32768 + cur * 256);

        bf16x8 kf[2];
        {
            int row = w16 + l15;
#pragma unroll
            for (int kk = 0; kk < 2; ++kk)
                kf[kk] = *(const bf16x8*)(KsC + row * 128 +
                                          ((kk * 64 + (g << 4)) ^ ((row & 7) << 4)));
        }
        s16x4 vvf[4];
#pragma unroll
        for (int dt = 0; dt < 4; ++dt) {
            int row = dt * 16 + l15;
            vvf[dt] = *(const s16x4*)(VsC + row * 128 +
                                      ((w16 * 2 + g * 8) ^ ((row & 7) << 4)));
        }
        f32x4 vm = *(const f32x4*)(biasC + w16 + 4 * g);

        f32x4 sc[4] = {};
#pragma unroll
        for (int kk = 0; kk < 2; ++kk)
#pragma unroll
            for (int qs = 0; qs < 4; ++qs)
                sc[qs] = __builtin_amdgcn_mfma_f32_16x16x32_bf16(
                    kf[kk], qf[qs][kk], sc[qs], 0, 0, 0);

        // all-ones fast path for this wave's 16 keys (bias == 0 exactly)
        int mv_ok = (vm[0] == 1.f) & (vm[1] == 1.f) & (vm[2] == 1.f) & (vm[3] == 1.f);
        if (!__all(mv_ok)) {
            f32x4 bbv;
#pragma unroll
            for (int r = 0; r < 4; ++r)
                bbv[r] = fmaf(vm[r], 1.442695e10f, -1.442695e10f);
#pragma unroll
            for (int qs = 0; qs < 4; ++qs)
#pragma unroll
                for (int r = 0; r < 4; ++r)
                    sc[qs][r] += bbv[r];
        }

        s16x4 pb[4];
#pragma unroll
        for (int qs = 0; qs < 4; ++qs)
#pragma unroll
            for (int r = 0; r < 4; ++r)
                pb[qs][r] = (short)f2b(__builtin_amdgcn_exp2f(sc[qs][r]));

        // O partial and l partial (l via ones-MFMA: every C row = column sum)
#pragma unroll
        for (int qs = 0; qs < 4; ++qs) {
#pragma unroll
            for (int dt = 0; dt < 4; ++dt)
                accO[qs][dt] = __builtin_amdgcn_mfma_f32_16x16x16bf16_1k(
                    vvf[dt], pb[qs], accO[qs][dt], 0, 0, 0);
            lacc[qs] = __builtin_amdgcn_mfma_f32_16x16x16bf16_1k(
                ones4, pb[qs], lacc[qs], 0, 0, 0);
        }

        __syncthreads();
    }

#pragma unroll
    for (int qs = 0; qs < 4; ++qs) lpart[qs] = lacc[qs][0];

    float* buf  = (float*)smem;                  // [qs][j][16 q][64 d]
    float* lred = (float*)(smem + 49152);        // [w][qs][16]

    if (g == 0)
#pragma unroll
        for (int qs = 0; qs < 4; ++qs)
            lred[(w * 4 + qs) * 16 + l15] = lpart[qs];

    f32x4 own[4] = {};
#pragma unroll
    for (int qs = 0; qs < 4; ++qs)
        if (qs == w) {
#pragma unroll
            for (int dt = 0; dt < 4; ++dt) own[dt] = accO[qs][dt];
        }

#pragma unroll
    for (int qs = 0; qs < 4; ++qs) {
        if (qs == w) continue;                   // runtime branch, static indices
        int j = (w < qs) ? w : w - 1;
        float* slot = buf + ((qs * 3 + j) * 16 + l15) * 64;
#pragma unroll
        for (int dt = 0; dt < 4; ++dt)
            *(f32x4*)(slot + dt * 16 + 4 * g) = accO[qs][dt];
    }
    __syncthreads();

    {
#pragma unroll
        for (int j = 0; j < 3; ++j) {
            const float* slot = buf + ((w * 3 + j) * 16 + l15) * 64;
#pragma unroll
            for (int dt = 0; dt < 4; ++dt)
                own[dt] += *(const f32x4*)(slot + dt * 16 + 4 * g);
        }
        float ltot = lred[(0 * 4 + w) * 16 + l15] + lred[(1 * 4 + w) * 16 + l15] +
                     lred[(2 * 4 + w) * 16 + l15] + lred[(3 * 4 + w) * 16 + l15];
        int qrow = q0 + w16 + l15;
        float qm = q_mask[(size_t)b * SEQ + qrow];
        float inv = (ltot > 0.f) ? qm / ltot : 0.f;
#pragma unroll
        for (int dt = 0; dt < 4; ++dt) {
            f32x4 o = own[dt] * inv;
            *(f32x4*)(&out[((size_t)b * SEQ + qrow) * 768 + h * HD + dt * 16 + 4 * g]) = o;
        }
    }
}

extern "C" void kernel_launch(void* const* d_in, const int* in_sizes, int n_in,
                              void* d_out, int out_size, void* d_ws, size_t ws_size,
                              hipStream_t stream) {
    const float* q      = (const float*)d_in[0];
    const float* k      = (const float*)d_in[1];
    const float* v      = (const float*)d_in[2];
    const float* vmask  = (const float*)d_in[3];
    const float* qmask  = (const float*)d_in[4];
    const float* Wq     = (const float*)d_in[5];
    const float* Wk     = (const float*)d_in[6];
    const float* Wv     = (const float*)d_in[7];
    float* out = (float*)d_out;

    u16* WTq = (u16*)d_ws;
    u16* WTk = WTq + (size_t)DMODEL * DMODEL;
    u16* WTv = WTk + (size_t)DMODEL * DMODEL;
    u16* qwp = WTv + (size_t)DMODEL * DMODEL;
    u16* kwp = qwp + (size_t)BATCH * HEADS * SEQ * HD;
    u16* vtp = kwp + (size_t)BATCH * HEADS * SEQ * HD;

    cvt_wt<<<dim3(DMODEL / 32, DMODEL / 32, 3), dim3(32, 8), 0, stream>>>(
        Wq, Wk, Wv, WTq, WTk, WTv);
    proj_gemm<<<dim3(BS / 128, DMODEL / 96, 3), 256, 0, stream>>>(
        q, k, v, WTq, WTk, WTv, qwp, kwp, vtp);
    attn<<<dim3(SEQ / 64, BATCH * HEADS), 256, 0, stream>>>(
        qwp, kwp, vtp, vmask, qmask, out);
}